// Round 2
// baseline (19666.443 us; speedup 1.0000x reference)
//
#include <hip/hip_runtime.h>
#include <hip/hip_bf16.h>

// Problem constants (match reference)
#define Tn 2048
#define Bn 32
#define Dn 256
#define Un 256
// 4U = 1024 gate columns, split as [i|f|g|o] blocks of 256.

using short8 = __attribute__((ext_vector_type(8))) short;
using f32x4  = __attribute__((ext_vector_type(4))) float;

__device__ __forceinline__ unsigned short f2bf(float f) {
    unsigned int u = __builtin_bit_cast(unsigned int, f);
    u += 0x7fffu + ((u >> 16) & 1u);   // round-to-nearest-even
    return (unsigned short)(u >> 16);
}
__device__ __forceinline__ float bf2f(unsigned short v) {
    unsigned int u = ((unsigned int)v) << 16;
    return __builtin_bit_cast(float, u);
}
__device__ __forceinline__ float rcp_f(float x) { return __builtin_amdgcn_rcpf(x); }
__device__ __forceinline__ float sigm(float x)   { return rcp_f(1.0f + __expf(-x)); }
__device__ __forceinline__ float tanh_f(float x) { return 1.0f - 2.0f * rcp_f(__expf(2.0f * x) + 1.0f); }

// ---------------------------------------------------------------------------
// Kernel 1: zx = data @ Wx, stored bf16, layout [T][B][1024]. (Unchanged from
// round 1 — passed, ~100us.)
// ---------------------------------------------------------------------------
__global__ __launch_bounds__(512) void gemm_zx(const float* __restrict__ data,
                                               const float* __restrict__ Wx,
                                               unsigned short* __restrict__ zws)
{
    __shared__ unsigned short BsubT[128 * 40];

    const int bid = blockIdx.x;
    const int bn = bid & 7;
    const int bm = bid >> 3;
    const int tid = threadIdx.x;
    const int lane = tid & 63, wid = tid >> 6;
    const int wm = wid >> 2, wn = wid & 3;
    const int l15 = lane & 15, lk = lane >> 4;

    f32x4 acc[4][2];
    #pragma unroll
    for (int mt = 0; mt < 4; ++mt)
        #pragma unroll
        for (int nt = 0; nt < 2; ++nt)
            acc[mt][nt] = f32x4{0.f, 0.f, 0.f, 0.f};

    const int colStage = tid & 127;
    const int kqStage  = tid >> 7;

    for (int ks = 0; ks < 8; ++ks) {
        __syncthreads();
        {
            const float* wp = Wx + (size_t)(ks * 32 + kqStage) * 1024 + bn * 128 + colStage;
            #pragma unroll
            for (int kk = 0; kk < 8; ++kk) {
                float v = wp[(size_t)kk * 4 * 1024];
                BsubT[colStage * 40 + (kqStage + kk * 4)] = f2bf(v);
            }
        }
        __syncthreads();

        short8 afr[4];
        #pragma unroll
        for (int mt = 0; mt < 4; ++mt) {
            int row = bm * 128 + wm * 64 + mt * 16 + l15;
            const float* ap = data + (size_t)row * 256 + ks * 32 + lk * 8;
            float4 a0 = *(const float4*)(ap);
            float4 a1 = *(const float4*)(ap + 4);
            short8 a;
            a[0] = (short)f2bf(a0.x); a[1] = (short)f2bf(a0.y);
            a[2] = (short)f2bf(a0.z); a[3] = (short)f2bf(a0.w);
            a[4] = (short)f2bf(a1.x); a[5] = (short)f2bf(a1.y);
            a[6] = (short)f2bf(a1.z); a[7] = (short)f2bf(a1.w);
            afr[mt] = a;
        }
        #pragma unroll
        for (int nt = 0; nt < 2; ++nt) {
            int colL = wn * 32 + nt * 16 + l15;
            short8 bfr = *(const short8*)&BsubT[colL * 40 + lk * 8];
            #pragma unroll
            for (int mt = 0; mt < 4; ++mt)
                acc[mt][nt] = __builtin_amdgcn_mfma_f32_16x16x32_bf16(afr[mt], bfr, acc[mt][nt], 0, 0, 0);
        }
    }

    #pragma unroll
    for (int mt = 0; mt < 4; ++mt) {
        #pragma unroll
        for (int nt = 0; nt < 2; ++nt) {
            int col = bn * 128 + wn * 32 + nt * 16 + l15;
            #pragma unroll
            for (int r = 0; r < 4; ++r) {
                int row = bm * 128 + wm * 64 + mt * 16 + lk * 4 + r;
                int b_ = row >> 11;
                int t_ = row & 2047;
                zws[(size_t)(t_ * 32 + b_) * 1024 + col] = f2bf(acc[mt][nt][r]);
            }
        }
    }
}

// ---------------------------------------------------------------------------
// Kernel 1b: WhT[col][k] = bf16(Wh[k][col]) — one-time transpose so the
// recurrent kernel's B-fragments are contiguous 16B loads.
// ---------------------------------------------------------------------------
__global__ void wh_transpose(const float* __restrict__ Wh,
                             unsigned short* __restrict__ WhT)
{
    const int c = blockIdx.x;    // 0..1023 (gate column)
    const int k = threadIdx.x;   // 0..255
    WhT[c * 256 + k] = f2bf(Wh[(size_t)k * 1024 + c]);
}

// ---------------------------------------------------------------------------
// Kernel 2: recurrence, batch-split. 2 independent blocks x 16 batches.
// No inter-block communication: h in LDS (double-buffered, XOR-swizzled),
// c in registers, Wh streamed from L2 every step (bf16, [col][k] layout).
// 512 threads = 8 waves; wave w owns gate-cols {g*256 + w*32 .. +32}.
// Per step: 64 MFMA/wave (1 m-tile x 8 n-tiles x 8 k-steps), then gate math
// entirely thread-local (C-frag cols of all 4 gates land in the same lane).
// ---------------------------------------------------------------------------
__global__ __launch_bounds__(512, 2) void lstm_rec(
    const unsigned short* __restrict__ WhT,   // [1024][256] bf16
    const float* __restrict__ bias,           // [1024]
    const unsigned short* __restrict__ zws,   // [T][32][1024] bf16
    float* __restrict__ out)                  // [32][T][256] f32
{
    const int bq = blockIdx.x;                // 0..1: batches bq*16 .. +16
    __shared__ __align__(16) char hb[2][8192];  // h double-buffer: [16 rows][256 u] bf16, XOR-swizzled

    const int tid = threadIdx.x;
    const int lane = tid & 63, w = tid >> 6;   // 8 waves
    const int l15 = lane & 15, lk = lane >> 4; // lk in 0..3

    // zero h(t=-1)
    {
        short8 z8 = {0, 0, 0, 0, 0, 0, 0, 0};
        *(short8*)(hb[0] + tid * 16) = z8;
    }

    // bias registers: [gate][half] for u = w*32 + half*16 + l15
    float bias_r[4][2];
    #pragma unroll
    for (int g = 0; g < 4; ++g)
        #pragma unroll
        for (int hf = 0; hf < 2; ++hf)
            bias_r[g][hf] = bias[g * 256 + w * 32 + hf * 16 + l15];

    float c_state[2][4];
    #pragma unroll
    for (int hf = 0; hf < 2; ++hf)
        #pragma unroll
        for (int r = 0; r < 4; ++r)
            c_state[hf][r] = 0.0f;

    // zx prefetch for t=0: [gate][half][r], b = bq*16 + lk*4 + r
    unsigned short zx_pf[4][2][4];
    #pragma unroll
    for (int g = 0; g < 4; ++g)
        #pragma unroll
        for (int hf = 0; hf < 2; ++hf)
            #pragma unroll
            for (int r = 0; r < 4; ++r)
                zx_pf[g][hf][r] = zws[(size_t)(bq * 16 + lk * 4 + r) * 1024
                                      + g * 256 + w * 32 + hf * 16 + l15];

    // B-fragment double buffer; prologue: k-steps 0 and 1.
    // nt = g*2 + half; col = (nt>>1)*256 + w*32 + (nt&1)*16 + l15
    short8 Bf[2][8];
    #pragma unroll
    for (int nt = 0; nt < 8; ++nt) {
        const int cb = (nt >> 1) * 256 + w * 32 + (nt & 1) * 16 + l15;
        Bf[0][nt] = *(const short8*)(WhT + cb * 256 + 0 * 32 + lk * 8);
        Bf[1][nt] = *(const short8*)(WhT + cb * 256 + 1 * 32 + lk * 8);
    }

    __syncthreads();

    for (int t = 0; t < Tn; ++t) {
        const char* hcur = hb[t & 1];
        char* hnxt = (char*)hb[(t + 1) & 1];

        // A fragments from LDS h-buffer (double-buffered regs, swizzled reads)
        short8 Af[2];
        Af[0] = *(const short8*)(hcur + l15 * 512 + (((lk * 8) * 2) ^ ((l15 & 7) << 4)));

        f32x4 acc[8];
        #pragma unroll
        for (int nt = 0; nt < 8; ++nt) acc[nt] = f32x4{0.f, 0.f, 0.f, 0.f};

        #pragma unroll
        for (int ks = 0; ks < 8; ++ks) {
            if (ks < 7) {
                const int k0 = (ks + 1) * 32 + lk * 8;
                Af[(ks + 1) & 1] = *(const short8*)(hcur + l15 * 512 + ((k0 * 2) ^ ((l15 & 7) << 4)));
            }
            #pragma unroll
            for (int nt = 0; nt < 8; ++nt)
                acc[nt] = __builtin_amdgcn_mfma_f32_16x16x32_bf16(Af[ks & 1], Bf[ks & 1][nt], acc[nt], 0, 0, 0);
            if (ks < 6) {
                // refill the buffer just consumed with k-step ks+2
                #pragma unroll
                for (int nt = 0; nt < 8; ++nt) {
                    const int cb = (nt >> 1) * 256 + w * 32 + (nt & 1) * 16 + l15;
                    Bf[ks & 1][nt] = *(const short8*)(WhT + cb * 256 + (ks + 2) * 32 + lk * 8);
                }
            }
        }

        // prefetch next step's k-steps 0,1 (Wh identical every step) — these
        // loads fly during the gate phase.
        #pragma unroll
        for (int nt = 0; nt < 8; ++nt) {
            const int cb = (nt >> 1) * 256 + w * 32 + (nt & 1) * 16 + l15;
            Bf[0][nt] = *(const short8*)(WhT + cb * 256 + 0 * 32 + lk * 8);
            Bf[1][nt] = *(const short8*)(WhT + cb * 256 + 1 * 32 + lk * 8);
        }

        // ---- gate phase: all operands thread-local
        #pragma unroll
        for (int hf = 0; hf < 2; ++hf) {
            #pragma unroll
            for (int r = 0; r < 4; ++r) {
                const float zi = acc[0 + hf][r] + bf2f(zx_pf[0][hf][r]) + bias_r[0][hf];
                const float zf = acc[2 + hf][r] + bf2f(zx_pf[1][hf][r]) + bias_r[1][hf];
                const float zg = acc[4 + hf][r] + bf2f(zx_pf[2][hf][r]) + bias_r[2][hf];
                const float zo = acc[6 + hf][r] + bf2f(zx_pf[3][hf][r]) + bias_r[3][hf];
                const float ig = sigm(zi), fg = sigm(zf);
                const float gg = tanh_f(zg), og = sigm(zo);
                const float cs = fg * c_state[hf][r] + ig * gg;
                c_state[hf][r] = cs;
                const float h = og * tanh_f(cs);

                const int b = lk * 4 + r;                 // local batch row 0..15
                const int u = w * 32 + hf * 16 + l15;     // unit 0..255
                out[(size_t)(bq * 16 + b) * (Tn * Un) + (size_t)t * Un + u] = h;
                *(unsigned short*)(hnxt + b * 512 + ((u * 2) ^ ((b & 7) << 4))) = f2bf(h);
            }
        }

        // zx prefetch for t+1
        if (t + 1 < Tn) {
            #pragma unroll
            for (int g = 0; g < 4; ++g)
                #pragma unroll
                for (int hf = 0; hf < 2; ++hf)
                    #pragma unroll
                    for (int r = 0; r < 4; ++r)
                        zx_pf[g][hf][r] = zws[(size_t)((t + 1) * 32 + bq * 16 + lk * 4 + r) * 1024
                                              + g * 256 + w * 32 + hf * 16 + l15];
        }

        __syncthreads();   // h(t) fully in LDS before anyone reads it at t+1
    }
}

// ---------------------------------------------------------------------------
extern "C" void kernel_launch(void* const* d_in, const int* in_sizes, int n_in,
                              void* d_out, int out_size, void* d_ws, size_t ws_size,
                              hipStream_t stream)
{
    const float* data = (const float*)d_in[0];   // [32,2048,256]
    const float* Wx   = (const float*)d_in[1];   // [256,1024]
    const float* Wh   = (const float*)d_in[2];   // [256,1024]
    const float* bias = (const float*)d_in[3];   // [1024]
    float* out = (float*)d_out;

    char* ws = (char*)d_ws;
    unsigned short* zws = (unsigned short*)ws;                 // 128 MB: [T][B][1024] bf16
    size_t zbytes = (size_t)Tn * Bn * 1024 * 2;
    unsigned short* WhT = (unsigned short*)(ws + zbytes);      // 512 KB: [1024][256] bf16

    wh_transpose<<<dim3(1024), dim3(256), 0, stream>>>(Wh, WhT);
    gemm_zx<<<dim3(4096), dim3(512), 0, stream>>>(data, Wx, zws);
    lstm_rec<<<dim3(2), dim3(512), 0, stream>>>(WhT, bias, zws, out);
}

// Round 3
// 5320.106 us; speedup vs baseline: 3.6966x; 3.6966x over previous
//
#include <hip/hip_runtime.h>
#include <hip/hip_bf16.h>

// Problem constants (match reference)
#define Tn 2048
#define Bn 32
#define Dn 256
#define Un 256
#define NBLK 16

using short8 = __attribute__((ext_vector_type(8))) short;
using f32x4  = __attribute__((ext_vector_type(4))) float;
using int4v  = __attribute__((ext_vector_type(4))) int;

__device__ __forceinline__ unsigned short f2bf(float f) {
    unsigned int u = __builtin_bit_cast(unsigned int, f);
    u += 0x7fffu + ((u >> 16) & 1u);   // round-to-nearest-even
    return (unsigned short)(u >> 16);
}
__device__ __forceinline__ float bf2f(unsigned short v) {
    unsigned int u = ((unsigned int)v) << 16;
    return __builtin_bit_cast(float, u);
}
__device__ __forceinline__ float rcp_f(float x) { return __builtin_amdgcn_rcpf(x); }
__device__ __forceinline__ float sigm(float x)   { return rcp_f(1.0f + __expf(-x)); }
__device__ __forceinline__ float tanh_f(float x) { return 1.0f - 2.0f * rcp_f(__expf(2.0f * x) + 1.0f); }

// ---------------------------------------------------------------------------
// Kernel 1: zx = data @ Wx, stored bf16, layout [T][B][1024]. (Unchanged —
// passed rounds 1-2, ~150us incl. transpose.)
// ---------------------------------------------------------------------------
__global__ __launch_bounds__(512) void gemm_zx(const float* __restrict__ data,
                                               const float* __restrict__ Wx,
                                               unsigned short* __restrict__ zws)
{
    __shared__ unsigned short BsubT[128 * 40];

    const int bid = blockIdx.x;
    const int bn = bid & 7;
    const int bm = bid >> 3;
    const int tid = threadIdx.x;
    const int lane = tid & 63, wid = tid >> 6;
    const int wm = wid >> 2, wn = wid & 3;
    const int l15 = lane & 15, lk = lane >> 4;

    f32x4 acc[4][2];
    #pragma unroll
    for (int mt = 0; mt < 4; ++mt)
        #pragma unroll
        for (int nt = 0; nt < 2; ++nt)
            acc[mt][nt] = f32x4{0.f, 0.f, 0.f, 0.f};

    const int colStage = tid & 127;
    const int kqStage  = tid >> 7;

    for (int ks = 0; ks < 8; ++ks) {
        __syncthreads();
        {
            const float* wp = Wx + (size_t)(ks * 32 + kqStage) * 1024 + bn * 128 + colStage;
            #pragma unroll
            for (int kk = 0; kk < 8; ++kk) {
                float v = wp[(size_t)kk * 4 * 1024];
                BsubT[colStage * 40 + (kqStage + kk * 4)] = f2bf(v);
            }
        }
        __syncthreads();

        short8 afr[4];
        #pragma unroll
        for (int mt = 0; mt < 4; ++mt) {
            int row = bm * 128 + wm * 64 + mt * 16 + l15;
            const float* ap = data + (size_t)row * 256 + ks * 32 + lk * 8;
            float4 a0 = *(const float4*)(ap);
            float4 a1 = *(const float4*)(ap + 4);
            short8 a;
            a[0] = (short)f2bf(a0.x); a[1] = (short)f2bf(a0.y);
            a[2] = (short)f2bf(a0.z); a[3] = (short)f2bf(a0.w);
            a[4] = (short)f2bf(a1.x); a[5] = (short)f2bf(a1.y);
            a[6] = (short)f2bf(a1.z); a[7] = (short)f2bf(a1.w);
            afr[mt] = a;
        }
        #pragma unroll
        for (int nt = 0; nt < 2; ++nt) {
            int colL = wn * 32 + nt * 16 + l15;
            short8 bfr = *(const short8*)&BsubT[colL * 40 + lk * 8];
            #pragma unroll
            for (int mt = 0; mt < 4; ++mt)
                acc[mt][nt] = __builtin_amdgcn_mfma_f32_16x16x32_bf16(afr[mt], bfr, acc[mt][nt], 0, 0, 0);
        }
    }

    #pragma unroll
    for (int mt = 0; mt < 4; ++mt) {
        #pragma unroll
        for (int nt = 0; nt < 2; ++nt) {
            int col = bn * 128 + wn * 32 + nt * 16 + l15;
            #pragma unroll
            for (int r = 0; r < 4; ++r) {
                int row = bm * 128 + wm * 64 + mt * 16 + lk * 4 + r;
                int b_ = row >> 11;
                int t_ = row & 2047;
                zws[(size_t)(t_ * 32 + b_) * 1024 + col] = f2bf(acc[mt][nt][r]);
            }
        }
    }
}

// ---------------------------------------------------------------------------
// Kernel 1b: WhT[col][k] = bf16(Wh[k][col]) — one-time transpose.
// ---------------------------------------------------------------------------
__global__ void wh_transpose(const float* __restrict__ Wh,
                             unsigned short* __restrict__ WhT)
{
    const int c = blockIdx.x;    // 0..1023 (gate column)
    const int k = threadIdx.x;   // 0..255
    WhT[c * 256 + k] = f2bf(Wh[(size_t)k * 1024 + c]);
}

// ---------------------------------------------------------------------------
// Kernel 2: recurrence. 16 blocks x 128 threads (2 waves). Block owns 16 u's;
// its 64 gate-columns of Wh live in REGISTERS (Bf[4][8] short8 = 128 VGPR).
// Wave mt handles batches mt*16..+16 and all 4 gates -> gate math is fully
// thread-local: no LDS, one barrier/step.
// h exchange through LLC: UC stores/loads (sc0 sc1 - no cache flushes),
// single-writer per-block flags (relaxed agent atomics, separate lines).
// ---------------------------------------------------------------------------
__global__ __launch_bounds__(128) void lstm_rec(
    const unsigned short* __restrict__ WhT,   // [1024][256] bf16
    const float* __restrict__ bias,           // [1024]
    const unsigned short* __restrict__ zws,   // [T][32][1024] bf16
    unsigned short* __restrict__ hG,          // [2][32][256] bf16
    unsigned int* __restrict__ flagB,         // [16] x 32-uint stride (128B lines)
    float* __restrict__ out)                  // [32][T][256] f32
{
    const int chunk = blockIdx.x;             // 0..15
    const int tid = threadIdx.x;
    const int lane = tid & 63;
    const int mt = tid >> 6;                  // wave: m-tile 0..1
    const int l15 = lane & 15, lk = lane >> 4;

    const int u = chunk * 16 + l15;           // this lane's unit (gate col base)

    // ---- one-time: Wh fragments into registers. Bf[g][ks]: B-operand for
    // gate g, k-step ks. col = g*256+u, k = ks*32 + lk*8.
    short8 Bf[4][8];
    #pragma unroll
    for (int g = 0; g < 4; ++g)
        #pragma unroll
        for (int ks = 0; ks < 8; ++ks)
            Bf[g][ks] = *(const short8*)(WhT + (size_t)(g * 256 + u) * 256 + ks * 32 + lk * 8);

    float bias_r[4];
    #pragma unroll
    for (int g = 0; g < 4; ++g) bias_r[g] = bias[g * 256 + u];

    float c_state[4];
    #pragma unroll
    for (int r = 0; r < 4; ++r) c_state[r] = 0.0f;

    // zx prefetch for t=0: b = mt*16 + lk*4 + r
    unsigned short zx_pf[4][4];
    #pragma unroll
    for (int g = 0; g < 4; ++g)
        #pragma unroll
        for (int r = 0; r < 4; ++r)
            zx_pf[g][r] = zws[(size_t)(mt * 16 + lk * 4 + r) * 1024 + g * 256 + u];

    for (int t = 0; t < Tn; ++t) {
        f32x4 acc[4];
        #pragma unroll
        for (int g = 0; g < 4; ++g) acc[g] = f32x4{0.f, 0.f, 0.f, 0.f};

        if (t > 0) {
            // ---- wait for all 16 producers of h(t-1). Lane j polls block
            // (j&15)'s flag; single-writer, no RMW contention.
            const unsigned int* fp = flagB + (size_t)(lane & 15) * 32;
            unsigned int v;
            do {
                v = __hip_atomic_load(fp, __ATOMIC_RELAXED, __HIP_MEMORY_SCOPE_AGENT);
            } while (!__all((int)(v >= (unsigned int)t)));

            // ---- A-fragments: UC loads straight from LLC (bypass stale L1/L2)
            const unsigned short* hp = hG + (size_t)((t - 1) & 1) * (32 * 256);
            int4v Afr[8];
            #pragma unroll
            for (int ks = 0; ks < 8; ++ks) {
                unsigned long long aaddr =
                    (unsigned long long)(hp + (size_t)(mt * 16 + l15) * 256 + ks * 32 + lk * 8);
                asm volatile("global_load_dwordx4 %0, %1, off sc0 sc1"
                             : "=v"(Afr[ks]) : "v"(aaddr) : "memory");
            }
            asm volatile("s_waitcnt vmcnt(0)" ::: "memory");
            __builtin_amdgcn_sched_barrier(0);

            // ---- 32 MFMA: 4 independent 8-deep chains (one per gate)
            #pragma unroll
            for (int ks = 0; ks < 8; ++ks) {
                short8 af = __builtin_bit_cast(short8, Afr[ks]);
                #pragma unroll
                for (int g = 0; g < 4; ++g)
                    acc[g] = __builtin_amdgcn_mfma_f32_16x16x32_bf16(af, Bf[g][ks], acc[g], 0, 0, 0);
            }
        }

        // ---- gate phase: thread-local. lane holds (u, b = mt*16+lk*4+r).
        float hval[4];
        #pragma unroll
        for (int r = 0; r < 4; ++r) {
            const float zi = acc[0][r] + bf2f(zx_pf[0][r]) + bias_r[0];
            const float zf = acc[1][r] + bf2f(zx_pf[1][r]) + bias_r[1];
            const float zg = acc[2][r] + bf2f(zx_pf[2][r]) + bias_r[2];
            const float zo = acc[3][r] + bf2f(zx_pf[3][r]) + bias_r[3];
            const float ig = sigm(zi), fg = sigm(zf);
            const float gg = tanh_f(zg), og = sigm(zo);
            const float cs = fg * c_state[r] + ig * gg;
            c_state[r] = cs;
            hval[r] = og * tanh_f(cs);
        }

        // ---- publish h(t): UC stores (write-through to LLC)
        unsigned short* hw = hG + (size_t)(t & 1) * (32 * 256);
        #pragma unroll
        for (int r = 0; r < 4; ++r) {
            const int b = mt * 16 + lk * 4 + r;
            unsigned long long haddr = (unsigned long long)(hw + (size_t)b * 256 + u);
            unsigned int hb = (unsigned int)f2bf(hval[r]);
            asm volatile("global_store_short %0, %1, off sc0 sc1"
                         :: "v"(haddr), "v"(hb) : "memory");
        }
        asm volatile("s_waitcnt vmcnt(0)" ::: "memory");   // own stores acked at LLC
        __syncthreads();                                    // all threads' stores acked
        if (tid == 0)
            __hip_atomic_store(&flagB[(size_t)chunk * 32], (unsigned int)(t + 1),
                               __ATOMIC_RELAXED, __HIP_MEMORY_SCOPE_AGENT);

        // ---- off critical path: output stores + next zx prefetch
        #pragma unroll
        for (int r = 0; r < 4; ++r) {
            const int b = mt * 16 + lk * 4 + r;
            out[(size_t)b * (Tn * Un) + (size_t)t * Un + u] = hval[r];
        }
        if (t + 1 < Tn) {
            #pragma unroll
            for (int g = 0; g < 4; ++g)
                #pragma unroll
                for (int r = 0; r < 4; ++r)
                    zx_pf[g][r] = zws[((size_t)(t + 1) * 32 + mt * 16 + lk * 4 + r) * 1024
                                      + g * 256 + u];
        }
    }
}

// ---------------------------------------------------------------------------
extern "C" void kernel_launch(void* const* d_in, const int* in_sizes, int n_in,
                              void* d_out, int out_size, void* d_ws, size_t ws_size,
                              hipStream_t stream)
{
    const float* data = (const float*)d_in[0];   // [32,2048,256]
    const float* Wx   = (const float*)d_in[1];   // [256,1024]
    const float* Wh   = (const float*)d_in[2];   // [256,1024]
    const float* bias = (const float*)d_in[3];   // [1024]
    float* out = (float*)d_out;

    char* ws = (char*)d_ws;
    unsigned short* zws = (unsigned short*)ws;                 // 128 MB: [T][B][1024] bf16
    size_t off = (size_t)Tn * Bn * 1024 * 2;
    unsigned short* WhT = (unsigned short*)(ws + off);         // 512 KB
    off += (size_t)1024 * 256 * 2;
    unsigned short* hG = (unsigned short*)(ws + off);          // 32 KB: [2][32][256]
    off += (size_t)2 * 32 * 256 * 2;
    unsigned int* flagB = (unsigned int*)(ws + off);           // 16 lines x 128 B

    hipMemsetAsync(flagB, 0, NBLK * 32 * sizeof(unsigned int), stream);

    wh_transpose<<<dim3(1024), dim3(256), 0, stream>>>(Wh, WhT);
    gemm_zx<<<dim3(4096), dim3(512), 0, stream>>>(data, Wx, zws);
    lstm_rec<<<dim3(NBLK), dim3(128), 0, stream>>>(WhT, bias, zws, hG, flagB, out);
}